// Round 14
// baseline (502.877 us; speedup 1.0000x reference)
//
#include <hip/hip_runtime.h>
#include <math.h>

typedef unsigned short u16;
typedef unsigned int u32;
typedef u16 u16x4 __attribute__((ext_vector_type(4)));
typedef float f32x2 __attribute__((ext_vector_type(2)));
typedef float f32x4 __attribute__((ext_vector_type(4)));
typedef __bf16 bf16x8 __attribute__((ext_vector_type(8)));

#define CAPF 256

__device__ __forceinline__ u16 f2bf(float f){
  u32 u = __builtin_bit_cast(u32, f);
  u32 r = u + 0x7FFFu + ((u >> 16) & 1u);
  return (u16)(r >> 16);
}
__device__ __forceinline__ float bf2f(u16 h){
  u32 u = ((u32)h) << 16;
  return __builtin_bit_cast(float, u);
}
__device__ __forceinline__ float ftanh(float x){
  float e = __expf(2.f*x);
  return 1.f - 2.f/(e+1.f);
}

typedef __attribute__((address_space(1))) const unsigned int gas_u32;
typedef __attribute__((address_space(3))) unsigned int las_u32;
__device__ __forceinline__ void gload_lds16(const void* g, void* l){
  __builtin_amdgcn_global_load_lds((gas_u32*)g, (las_u32*)l, 16, 0, 0);
}

// ---------------- prep0: fused cvt_xh + cvt_hilo(Wr) + zero(rawfix) + flag_rows ----------------
__global__ __launch_bounds__(256) void prep0(
    const float* __restrict__ x, const float* __restrict__ h,
    u16* __restrict__ cA, u16* __restrict__ xlo,
    const float* __restrict__ Wr, u16* __restrict__ Wr_hi, u16* __restrict__ Wr_lo,
    const float* __restrict__ bp, int* __restrict__ idx, int* __restrict__ smap,
    float* __restrict__ rawfix)
{
  const int bx = blockIdx.x, tid = threadIdx.x;
  if (bx < 12288){
    int b = bx / 3, cb = bx - b*3;
    int c0 = (cb*256 + tid)*4;
    f32x4 v;
    if (c0 < 1024) v = *(const f32x4*)(x + (size_t)b*1024 + c0);
    else           v = *(const f32x4*)(h + (size_t)b*2048 + (c0-1024));
    u16x4 hi4;
    #pragma unroll
    for (int j=0;j<4;++j) hi4[j]=f2bf(v[j]);
    *(u16x4*)(cA + (size_t)b*5120 + c0) = hi4;
    if (c0 < 1024){
      u16x4 lo4;
      #pragma unroll
      for (int j=0;j<4;++j) lo4[j]=f2bf(v[j]-bf2f(hi4[j]));
      *(u16x4*)(xlo + (size_t)b*1024 + c0) = lo4;
    }
  } else if (bx < 14336){
    int i = (bx-12288)*256 + tid;
    f32x4 v = *(const f32x4*)(Wr + (size_t)i*4);
    u16x4 oh, ol;
    #pragma unroll
    for (int j=0;j<4;++j){ u16 hh=f2bf(v[j]); oh[j]=hh; ol[j]=f2bf(v[j]-bf2f(hh)); }
    *(u16x4*)(Wr_hi + (size_t)i*4) = oh;
    *(u16x4*)(Wr_lo + (size_t)i*4) = ol;
  } else if (bx < 15104){
    int i = (bx-14336)*256 + tid;
    *(f32x4*)(rawfix + (size_t)i*4) = f32x4{0.f,0.f,0.f,0.f};
  } else {
    __shared__ int cnt;
    if (tid==0) cnt=0;
    __syncthreads();
    for (int i=tid; i<4096; i+=256){
      int p = -1;
      if (bp[i] < 0.04f){
        p = atomicAdd(&cnt,1);
        if (p < CAPF) idx[1+p]=i;
      }
      smap[i] = p;
    }
    __syncthreads();
    if (tid==0) idx[0] = min(cnt, CAPF);
  }
}

// ---------------- cvtW3 / cvt_hi ----------------
__global__ __launch_bounds__(256) void cvtW3(
    const float* __restrict__ W0, const float* __restrict__ W1, const float* __restrict__ W2,
    u16* __restrict__ out)
{
  int i = blockIdx.x*256 + threadIdx.x;
  int seg = i / 1310720;
  int w = i - seg*1310720;
  const float* src = (seg==0) ? W0 : (seg==1 ? W1 : W2);
  f32x4 v = *(const f32x4*)(src + (size_t)w*4);
  u16x4 o;
  #pragma unroll
  for (int j=0;j<4;++j) o[j]=f2bf(v[j]);
  *(u16x4*)(out + (size_t)seg*5242880 + (size_t)w*4) = o;
}

__global__ __launch_bounds__(256) void cvt_hi(const float* __restrict__ in, u16* __restrict__ out, int n4){
  int i = blockIdx.x*256 + threadIdx.x;
  if (i >= n4) return;
  f32x4 v = *(const f32x4*)(in + (size_t)i*4);
  u16x4 o;
  #pragma unroll
  for (int j=0;j<4;++j) o[j]=f2bf(v[j]);
  *(u16x4*)(out + (size_t)i*4) = o;
}

// ============ gemm2b: BM=128, BN=NF*32, 256 threads (4 waves 2Mx2N), BUFS-ring half-bufs ============
#define STG2B(U, BW) do{ int uc_ = min((U), NH-1); \
    const u16* sa_ = Ah + aS + (size_t)uc_*32; \
    u16* da_ = sA + (BW)*4096 + w4*512; \
    gload_lds16(sa_, da_); \
    gload_lds16(sa_ + (size_t)64*lda, da_ + 2048); \
    const u16* sb_ = Bh + bS + (size_t)uc_*32; \
    u16* db_ = sB + (BW)*BUFB + w4*512; \
    _Pragma("unroll") for (int j_=0;j_<BNC;++j_) \
      gload_lds16(sb_ + (size_t)(j_*64)*ldb, db_ + j_*2048); \
  }while(0)

template<int NF, int BUFS, bool OUTBF, int NB>
__global__ __launch_bounds__(256) void gemm2b(
    const u16* __restrict__ Ah, int lda,
    const u16* __restrict__ Bh, int ldb,
    const float* __restrict__ bias0, const float* __restrict__ bias1, const float* __restrict__ bias2,
    float* __restrict__ Cf, u16* __restrict__ Cb, int ldc, int K)
{
  constexpr int BN   = NF*32;
  constexpr int BNC  = BN/64;
  constexpr int LPH  = 2 + BNC;
  constexpr int VN   = (BUFS-2)*LPH;
  constexpr int BUFB = BN*32;
  __shared__ u16 sA[BUFS*4096];
  __shared__ u16 sB[BUFS*BUFB];

  const int tid = threadIdx.x, lane = tid&63, w4 = tid>>6;
  const int wm = w4>>1, wn = w4&1;
  const int l16 = lane&15;

  const int gx = gridDim.x, nwg = gx*gridDim.y;
  const int lin = blockIdx.y*gx + blockIdx.x;
  const int sw = (lin&7)*(nwg>>3) + (lin>>3);
  const int m0 = (sw / gx)*128, n0 = (sw % gx)*BN;

  const int rowS = tid>>2;
  const int ksS  = (tid&3) ^ ((tid>>3)&3);
  const size_t aS = (size_t)(m0 + rowS)*lda + ksS*8;
  const size_t bS = (size_t)(n0 + rowS)*ldb + ksS*8;

  const int slot  = (lane>>4) ^ ((l16>>1)&3);
  const int abase = (wm*64 + l16)*32 + slot*8;
  const int bbase = (wn*(NF*16) + l16)*32 + slot*8;

  f32x4 acc[4][NF];
  #pragma unroll
  for (int a=0;a<4;++a)
    #pragma unroll
    for (int b=0;b<NF;++b) acc[a][b] = f32x4{0.f,0.f,0.f,0.f};

  const int NH = K>>5;

  #pragma unroll
  for (int u=0; u<BUFS-1; ++u){ STG2B(u, u); }
  asm volatile("s_waitcnt vmcnt(%0)" :: "i"(VN) : "memory");
  asm volatile("" ::: "memory");
  __builtin_amdgcn_s_barrier();

  int bufR = 0;
  for (int t=0; t<NH; ++t){
    int bufW = bufR + (BUFS-1); if (bufW >= BUFS) bufW -= BUFS;
    const u16* pa_ = sA + bufR*4096;
    const u16* pb_ = sB + bufR*BUFB;
    bf16x8 af0 = *(const bf16x8*)(pa_ + abase + 0*512);
    bf16x8 af1 = *(const bf16x8*)(pa_ + abase + 1*512);
    bf16x8 af2 = *(const bf16x8*)(pa_ + abase + 2*512);
    bf16x8 af3 = *(const bf16x8*)(pa_ + abase + 3*512);
    bf16x8 bfr[NF];
    #pragma unroll
    for (int n=0;n<NF;++n) bfr[n] = *(const bf16x8*)(pb_ + bbase + n*512);
    STG2B(t+BUFS-1, bufW);
    asm volatile("" ::: "memory");
    __builtin_amdgcn_s_barrier();
    __builtin_amdgcn_s_setprio(1);
    #pragma unroll
    for (int n=0;n<NF;++n){
      acc[0][n] = __builtin_amdgcn_mfma_f32_16x16x32_bf16(af0, bfr[n], acc[0][n],0,0,0);
      acc[1][n] = __builtin_amdgcn_mfma_f32_16x16x32_bf16(af1, bfr[n], acc[1][n],0,0,0);
      acc[2][n] = __builtin_amdgcn_mfma_f32_16x16x32_bf16(af2, bfr[n], acc[2][n],0,0,0);
      acc[3][n] = __builtin_amdgcn_mfma_f32_16x16x32_bf16(af3, bfr[n], acc[3][n],0,0,0);
    }
    __builtin_amdgcn_s_setprio(0);
    asm volatile("s_waitcnt vmcnt(%0)" :: "i"(VN) : "memory");
    asm volatile("" ::: "memory");
    __builtin_amdgcn_s_barrier();
    bufR = (bufR+1==BUFS) ? 0 : bufR+1;
  }
  asm volatile("s_waitcnt vmcnt(0)" ::: "memory");

  #pragma unroll
  for (int mf=0; mf<4; ++mf){
    int grow = m0 + wm*64 + mf*16 + (lane>>4)*4;
    #pragma unroll
    for (int n=0; n<NF; ++n){
      int gcol = n0 + wn*(NF*16) + n*16 + l16;
      float bb;
      if constexpr(NB==3) bb = (gcol<1024) ? bias0[gcol] : ((gcol<2048) ? bias1[gcol-1024] : bias2[gcol-2048]);
      else bb = bias0[gcol];
      #pragma unroll
      for (int r2=0;r2<4;++r2){
        float v = acc[mf][n][r2] + bb;
        if constexpr(OUTBF) Cb[(size_t)(grow+r2)*ldc + gcol] = f2bf(v);
        else                Cf[(size_t)(grow+r2)*ldc + gcol] = v;
      }
    }
  }
}

// ============ gemm8p: 8-phase 256-row GEMM (fio: NR=3 -> BN=192 exact-fill) ============
#define LDA8(BUF,H,MH,J) (*(const bf16x8*)(sAc + ((BUF)*2+(H))*16384 + abase + (MH)*4096 + (J)*1024))
#define LDB8(BUF,H,N)    (*(const bf16x8*)(sBc + ((BUF)*2+(H))*16384 + bbase + (N)*1024))
#define STG_A8(BUF,H,TT) { const u16* s_ = Ah + aS + (size_t)(TT)*64 + (H)*32; \
    gload_lds16(s_, dA + ((BUF)*2+(H))*8192); \
    gload_lds16(s_ + aS2, dA + ((BUF)*2+(H))*8192 + 4096); }
#define STG_B8(BUF,H,TT) { const u16* s_ = Bh + bS + (size_t)(TT)*64 + (H)*32; \
    gload_lds16(s_, dB + ((BUF)*2+(H))*8192); \
    gload_lds16(s_ + bS2, dB + ((BUF)*2+(H))*8192 + 4096); }
#define PH8(BUF,H,MH,RB,STG,DOW) do{ \
    bf16x8 af0 = LDA8(BUF,H,MH,0), af1 = LDA8(BUF,H,MH,1), af2 = LDA8(BUF,H,MH,2), af3 = LDA8(BUF,H,MH,3); \
    if (RB){ _Pragma("unroll") for(int n_=0;n_<NR;++n_) bfr[n_] = LDB8(BUF,H,n_); } \
    STG; \
    asm volatile("" ::: "memory"); \
    __builtin_amdgcn_s_barrier(); \
    __builtin_amdgcn_s_setprio(1); \
    _Pragma("unroll") for(int n_=0;n_<NR;++n_){ \
      acc[(MH)*4+0][n_] = __builtin_amdgcn_mfma_f32_16x16x32_bf16(af0, bfr[n_], acc[(MH)*4+0][n_],0,0,0); \
      acc[(MH)*4+1][n_] = __builtin_amdgcn_mfma_f32_16x16x32_bf16(af1, bfr[n_], acc[(MH)*4+1][n_],0,0,0); \
      acc[(MH)*4+2][n_] = __builtin_amdgcn_mfma_f32_16x16x32_bf16(af2, bfr[n_], acc[(MH)*4+2][n_],0,0,0); \
      acc[(MH)*4+3][n_] = __builtin_amdgcn_mfma_f32_16x16x32_bf16(af3, bfr[n_], acc[(MH)*4+3][n_],0,0,0); } \
    __builtin_amdgcn_s_setprio(0); \
    if (DOW) { asm volatile("s_waitcnt vmcnt(%0)" :: "i"(VN) : "memory"); } \
    asm volatile("" ::: "memory"); \
    __builtin_amdgcn_s_barrier(); \
  }while(0)

template<int NR, bool OUTBF, int NB>
__global__ __launch_bounds__(512) void gemm8p(
    const u16* __restrict__ Ah, int lda,
    const u16* __restrict__ Bh, int ldb,
    const float* __restrict__ bias0, const float* __restrict__ bias1, const float* __restrict__ bias2,
    float* __restrict__ Cf, u16* __restrict__ Cb, int ldc, int K)
{
  constexpr int VN   = 8;
  __shared__ u16 sA[4*8192];
  __shared__ u16 sB[4*8192];
  const char* sAc = (const char*)sA;
  const char* sBc = (const char*)sB;

  const int tid = threadIdx.x, lane = tid&63, w8 = tid>>6;
  const int wr = w8>>2, wc = w8&3;
  const int l16 = lane&15;

  const int gx = gridDim.x, nwg = gx*gridDim.y;
  const int lin = blockIdx.y*gx + blockIdx.x;
  const int sw = (lin&7)*(nwg>>3) + (lin>>3);
  const int m0 = (sw / gx)*256, n0 = (sw % gx)*(NR*64);

  const int rowS  = tid>>2;
  const int ksS   = (tid&3) ^ ((tid>>3)&3);
  const size_t aS = (size_t)(m0 + rowS)*lda + ksS*8;
  const size_t aS2= (size_t)128*lda;
  const size_t bS = (size_t)(n0 + rowS)*ldb + ksS*8;
  const size_t bS2= (size_t)128*ldb;
  u16* dA = sA + w8*512;
  u16* dB = sB + w8*512;

  const int aslot = (lane>>4) ^ ((l16>>1)&3);
  const int abase = (wr*128 + l16)*64 + aslot*16;
  const int bbase = (wc*(NR*16) + l16)*64 + aslot*16;

  f32x4 acc[8][NR];
  #pragma unroll
  for (int a=0;a<8;++a)
    #pragma unroll
    for (int b=0;b<NR;++b) acc[a][b] = f32x4{0.f,0.f,0.f,0.f};
  bf16x8 bfr[NR];

  const int NT = K>>6, NITER = K>>7;

  STG_A8(0,0,0) STG_B8(0,0,0) STG_A8(0,1,0) STG_B8(0,1,0) STG_A8(1,0,1) STG_B8(1,0,1)
  asm volatile("s_waitcnt vmcnt(%0)" :: "i"(VN) : "memory");
  asm volatile("" ::: "memory");
  __builtin_amdgcn_s_barrier();

  for (int i=0; i<NITER; ++i){
    const int t1 = 2*i+1;
    const int ta = min(2*i+2, NT-1);
    const int tb = min(2*i+3, NT-1);
    PH8(0,0,0,true,  STG_A8(1,1,t1), false);
    PH8(0,0,1,false, STG_B8(1,1,t1), true);
    PH8(0,1,0,true,  STG_A8(0,0,ta), false);
    PH8(0,1,1,false, STG_B8(0,0,ta), true);
    PH8(1,0,0,true,  STG_A8(0,1,ta), false);
    PH8(1,0,1,false, STG_B8(0,1,ta), true);
    PH8(1,1,0,true,  STG_A8(1,0,tb), false);
    PH8(1,1,1,false, STG_B8(1,0,tb), true);
  }
  asm volatile("s_waitcnt vmcnt(0)" ::: "memory");

  #pragma unroll
  for (int mf=0; mf<8; ++mf){
    int grow = m0 + wr*128 + mf*16 + (lane>>4)*4;
    #pragma unroll
    for (int n=0; n<NR; ++n){
      int gcol = n0 + wc*(NR*16) + n*16 + l16;
      float bb;
      if constexpr(NB==3) bb = (gcol<1024) ? bias0[gcol] : ((gcol<2048) ? bias1[gcol-1024] : bias2[gcol-2048]);
      else bb = bias0[gcol];
      #pragma unroll
      for (int r2=0;r2<4;++r2){
        float v = acc[mf][n][r2] + bb;
        if constexpr(OUTBF) Cb[(size_t)(grow+r2)*ldc + gcol] = f2bf(v);
        else                Cf[(size_t)(grow+r2)*ldc + gcol] = v;
      }
    }
  }
}

// ============ gemm128: BM=128 BN=256 BK=32, BUFS-ring. SPLIT path fuses surfaced-epilogue ============
#define STG128(USRC, BW) do{ int u_=(USRC)<NT?(USRC):NT-1; \
    { const u16* s_=Ah+aS+(size_t)u_*32; gload_lds16(s_, sA+(BW)*4096+ldsb); } \
    { const u16* s_=Bh+bS+(size_t)u_*32; gload_lds16(s_, sB+(BW)*8192+ldsb); \
      gload_lds16(s_+bS2, sB+(BW)*8192+4096+ldsb); } \
    if constexpr(SPLIT){ \
      const u16* s2_=Al+aSl+(size_t)u_*32; gload_lds16(s2_, sAl+(BW)*4096+ldsb); \
      const u16* s3_=Bl+bS+(size_t)u_*32;  gload_lds16(s3_, sBl+(BW)*8192+ldsb); \
      gload_lds16(s3_+bS2, sBl+(BW)*8192+4096+ldsb); } \
  }while(0)

template<bool SPLIT, bool OUTBF, int BUFS>
__global__ __launch_bounds__(512) void gemm128(
    const u16* __restrict__ Ah, int lda,
    const u16* __restrict__ Al, int ldal,
    const u16* __restrict__ Bh, int ldb,
    const u16* __restrict__ Bl,
    const float* __restrict__ bias0,
    float* __restrict__ Cf, u16* __restrict__ Cb, int ldc, int K,
    const float* __restrict__ dprev, const int* __restrict__ smap,
    float* __restrict__ Scmp, u16* __restrict__ cAs)
{
  constexpr int LPS = SPLIT ? 6 : 3;
  constexpr int VN  = (BUFS-2)*LPS;
  constexpr int PRE = BUFS-1;
  __shared__ u16 sA [BUFS*4096];
  __shared__ u16 sB [BUFS*8192];
  __shared__ u16 sAl[SPLIT?BUFS*4096:8];
  __shared__ u16 sBl[SPLIT?BUFS*8192:8];

  const int tid=threadIdx.x, lane=tid&63, w8=tid>>6;
  const int wr=w8>>2, wc=w8&3, l16=lane&15;

  const int gx=gridDim.x, nwg=gx*gridDim.y;
  const int lin=blockIdx.y*gx+blockIdx.x;
  const int sw=(lin&7)*(nwg>>3)+(lin>>3);
  const int m0=(sw/gx)*128, n0=(sw%gx)*256;

  const int rowS=tid>>2;
  const int ksS=(tid&3)^((tid>>3)&3);
  const size_t aS =(size_t)(m0+rowS)*lda  + ksS*8;
  const size_t aSl=(size_t)(m0+rowS)*(size_t)ldal + ksS*8;
  const size_t bS =(size_t)(n0+rowS)*ldb  + ksS*8;
  const size_t bS2=(size_t)128*ldb;
  const int ldsb = w8*512;

  const int aslot=(lane>>4)^((l16>>1)&3);
  const int abase=(wr*64+l16)*64 + aslot*16;
  const int bbase=(wc*64+l16)*64 + aslot*16;

  f32x4 acc[4][4];
  #pragma unroll
  for (int a=0;a<4;++a)
    #pragma unroll
    for (int b=0;b<4;++b) acc[a][b] = f32x4{0.f,0.f,0.f,0.f};

  const int NT = K>>5;

  #pragma unroll
  for (int u=0; u<PRE; ++u){ STG128(u,u); }
  asm volatile("s_waitcnt vmcnt(%0)" :: "i"(VN) : "memory");
  asm volatile("" ::: "memory");
  __builtin_amdgcn_s_barrier();

  int bufR = 0;
  for (int t=0; t<NT; ++t){
    int bufW = (bufR==0) ? BUFS-1 : bufR-1;
    const char* sAc=(const char*)sA  + bufR*8192;
    const char* sBc=(const char*)sB  + bufR*16384;
    const char* sAlc=(const char*)sAl + bufR*8192;
    const char* sBlc=(const char*)sBl + bufR*16384;
    bf16x8 af[4], bf[4], afl[4], bfl[4];
    #pragma unroll
    for (int f=0; f<4; ++f){
      af[f] = *(const bf16x8*)(sAc + abase + f*1024);
      bf[f] = *(const bf16x8*)(sBc + bbase + f*1024);
      if constexpr(SPLIT){
        afl[f] = *(const bf16x8*)(sAlc + abase + f*1024);
        bfl[f] = *(const bf16x8*)(sBlc + bbase + f*1024);
      }
    }
    STG128(t+PRE, bufW);
    asm volatile("" ::: "memory");
    __builtin_amdgcn_s_barrier();
    __builtin_amdgcn_s_setprio(1);
    #pragma unroll
    for (int mf=0; mf<4; ++mf){
      #pragma unroll
      for (int nf=0; nf<4; ++nf){
        acc[mf][nf] = __builtin_amdgcn_mfma_f32_16x16x32_bf16(af[mf], bf[nf], acc[mf][nf],0,0,0);
        if constexpr(SPLIT){
          acc[mf][nf] = __builtin_amdgcn_mfma_f32_16x16x32_bf16(afl[mf], bf[nf],  acc[mf][nf],0,0,0);
          acc[mf][nf] = __builtin_amdgcn_mfma_f32_16x16x32_bf16(af[mf],  bfl[nf], acc[mf][nf],0,0,0);
        }
      }
    }
    __builtin_amdgcn_s_setprio(0);
    asm volatile("s_waitcnt vmcnt(%0)" :: "i"(VN) : "memory");
    asm volatile("" ::: "memory");
    __builtin_amdgcn_s_barrier();
    bufR = (bufR+1==BUFS) ? 0 : bufR+1;
  }
  asm volatile("s_waitcnt vmcnt(0)" ::: "memory");

  #pragma unroll
  for (int mf=0; mf<4; ++mf){
    int grow = m0 + wr*64 + mf*16 + (lane>>4)*4;
    #pragma unroll
    for (int nf=0; nf<4; ++nf){
      int gcol = n0 + wc*64 + nf*16 + l16;
      float bb = bias0[gcol];
      #pragma unroll
      for (int r2=0;r2<4;++r2){
        float v = acc[mf][nf][r2] + bb;
        if constexpr(SPLIT){
          // fused surfaced epilogue: pair (re,im) via lane exchange; even lanes compute
          float w = __shfl_xor(v, 1);
          if ((l16 & 1) == 0){
            int row = grow + r2;
            float zre = v + 1e-10f, zim = w;
            f32x2 d = *(const f32x2*)(dprev + (size_t)row*2048 + gcol);
            float dx = d[0] + 1e-10f;
            float hz = sqrtf(zre*zre + zim*zim);
            float hd = sqrtf(dx*dx + d[1]*d[1]);
            float cosd = (zre*dx + zim*d[1]) / fmaxf(hz*hd, 1e-30f);
            float T = 0.5f + 0.5f*cosd;
            float dmag = sqrtf(d[0]*d[0] + d[1]*d[1] + 1e-8f);
            float dscale = sqrtf(fminf(fmaxf(dmag, 1e-6f), 20.0f));
            float s = T * dscale / (dmag + 1e-8f);
            float o0 = d[0]*s, o1 = d[1]*s;
            u32 pk = (u32)f2bf(o0) | ((u32)f2bf(o1) << 16);
            *(u32*)&cAs[(size_t)row*5120 + 3072 + gcol] = pk;
            int p = smap[row];
            if (p >= 0 && p < CAPF)
              *(f32x2*)(Scmp + (size_t)p*2048 + gcol) = f32x2{o0, o1};
          }
        } else if constexpr(OUTBF) {
          Cb[(size_t)(grow+r2)*ldc + gcol] = f2bf(v);
        } else {
          Cf[(size_t)(grow+r2)*ldc + gcol] = v;
        }
      }
    }
  }
}

// ---------------- fixup: precise 3-pass for flagged rows, SPLIT-K, compact output ----------------
#define LSTR 40
#define FIX_KC 16
#define FIX_KLEN 320
__global__ __launch_bounds__(256) void gemm_fix_sk(
    const float* __restrict__ Xs, const float* __restrict__ Hs,
    const float* __restrict__ Scmp, const int* __restrict__ smap,
    const float* __restrict__ W0, const float* __restrict__ W1, const float* __restrict__ W2,
    const int* __restrict__ cr, float* __restrict__ Cfix)
{
  const int count = cr[0];
  const int m0 = blockIdx.y * 128;
  if (m0 >= count) return;
  const int* rows = cr + 1;
  const int kbeg = blockIdx.z * FIX_KLEN;
  const int kend = kbeg + FIX_KLEN;

  __shared__ u16 sAh[128*LSTR];
  __shared__ u16 sAl[128*LSTR];
  __shared__ u16 sBh[128*LSTR];
  __shared__ u16 sBl[128*LSTR];

  const int tid = threadIdx.x;
  const int n0 = blockIdx.x * 128;
  int seg = n0 >> 10;
  const float* W = (seg==0) ? W0 : (seg==1 ? W1 : W2);
  int nw = n0 & 1023;

  const int wave = tid >> 6, lane = tid & 63;
  const int wm = wave >> 1, wn = wave & 1;
  const int l16 = lane & 15, lk8 = (lane >> 4) * 8;

  f32x4 acc[4][4];
  #pragma unroll
  for (int a=0;a<4;++a)
    #pragma unroll
    for (int b=0;b<4;++b) acc[a][b] = f32x4{0.f,0.f,0.f,0.f};

  for (int k0 = kbeg; k0 < kend; k0 += 32){
    #pragma unroll
    for (int i=0;i<4;++i){
      int flat = tid + i*256;
      int r  = flat >> 3;
      int c4 = flat & 7;
      int kk = k0 + c4*4;
      int mi = min(m0 + r, count-1);
      int mrow = rows[mi];
      const float* srcA;
      if (kk < 1024)      srcA = Xs + (size_t)mrow*1024 + kk;
      else if (kk < 3072) srcA = Hs + (size_t)mrow*2048 + (kk - 1024);
      else                srcA = Scmp + (size_t)smap[mrow]*2048 + (kk - 3072);
      f32x4 va = *(const f32x4*)srcA;
      f32x4 vb = *(const f32x4*)(W + (size_t)(nw + r)*5120 + kk);
      u16x4 ah, bh, al, bl;
      #pragma unroll
      for (int j=0;j<4;++j){
        u16 hA = f2bf(va[j]); ah[j] = hA; al[j] = f2bf(va[j] - bf2f(hA));
        u16 hB = f2bf(vb[j]); bh[j] = hB; bl[j] = f2bf(vb[j] - bf2f(hB));
      }
      int o = r*LSTR + c4*4;
      *(u16x4*)&sAh[o] = ah;
      *(u16x4*)&sBh[o] = bh;
      *(u16x4*)&sAl[o] = al;
      *(u16x4*)&sBl[o] = bl;
    }
    __syncthreads();
    bf16x8 fah[4], fbh[4], fal[4], fbl[4];
    #pragma unroll
    for (int f=0; f<4; ++f){
      int ra  = (wm*64 + f*16 + l16)*LSTR + lk8;
      int rb2 = (wn*64 + f*16 + l16)*LSTR + lk8;
      fah[f] = *(const bf16x8*)&sAh[ra];
      fbh[f] = *(const bf16x8*)&sBh[rb2];
      fal[f] = *(const bf16x8*)&sAl[ra];
      fbl[f] = *(const bf16x8*)&sBl[rb2];
    }
    #pragma unroll
    for (int fm=0; fm<4; ++fm){
      #pragma unroll
      for (int fn=0; fn<4; ++fn){
        acc[fm][fn] = __builtin_amdgcn_mfma_f32_16x16x32_bf16(fah[fm], fbh[fn], acc[fm][fn], 0,0,0);
        acc[fm][fn] = __builtin_amdgcn_mfma_f32_16x16x32_bf16(fal[fm], fbh[fn], acc[fm][fn], 0,0,0);
        acc[fm][fn] = __builtin_amdgcn_mfma_f32_16x16x32_bf16(fah[fm], fbl[fn], acc[fm][fn], 0,0,0);
      }
    }
    __syncthreads();
  }

  #pragma unroll
  for (int fm=0; fm<4; ++fm){
    int trow = wm*64 + fm*16 + (lane>>4)*4;
    #pragma unroll
    for (int fn=0; fn<4; ++fn){
      int lcol = wn*64 + fn*16 + l16;
      #pragma unroll
      for (int r2=0;r2<4;++r2){
        int mi = m0 + trow + r2;
        if (mi < count){
          atomicAdd(&Cfix[(size_t)mi*3072 + (n0 + lcol)], acc[fm][fn][r2]);
        }
      }
    }
  }
}

// ---------------- epilogue (rawfio is bf16; flagged rows read compact rawfix + bias) ----------------
__global__ __launch_bounds__(256) void epilogue(
    const u16* __restrict__ rawfio, const u16* __restrict__ rawg,
    const float* __restrict__ rawfix, const int* __restrict__ smap, const int* __restrict__ cr,
    const float* __restrict__ bf0, const float* __restrict__ bf1, const float* __restrict__ bf2,
    const float* __restrict__ c_prev, const float* __restrict__ d_prev,
    const float* __restrict__ b_prev, const float* __restrict__ theta,
    float* __restrict__ out)
{
  const int b = blockIdx.x;
  const int tid = threadIdx.x;
  float* Hout = out;
  float* Cout = out + (size_t)8388608;
  float* Dout = out + (size_t)16777216;
  float* Bout = out + (size_t)25165824;
  const float bp = b_prev[b];
  const float inv_t = 1.0f / (2.0f*bp + 1e-4f);
  float conv_acc = 0.f, emer_acc = 0.f;
  const size_t rb3 = (size_t)b*3072;
  const size_t rg = (size_t)b*2048;
  const int p = smap[b];
  const bool fx = (p >= 0 && p < cr[0]);
  const size_t rfx = (size_t)p*3072;

  #pragma unroll
  for (int j=0;j<4;++j){
    int h = tid + j*256;
    float fr, ir, og;
    if (fx){
      fr = rawfix[rfx + h]        + bf0[h];
      ir = rawfix[rfx + 1024 + h] + bf1[h];
      og = rawfix[rfx + 2048 + h] + bf2[h];
    } else {
      fr = bf2f(rawfio[rb3 + h]);
      ir = bf2f(rawfio[rb3 + 1024 + h]);
      og = bf2f(rawfio[rb3 + 2048 + h]);
    }
    float g0 = bf2f(rawg[rg + h]);
    float g1 = bf2f(rawg[rg + 1024 + h]);

    float mx = fmaxf(fr, fmaxf(ir, og));
    float ef = __expf((fr-mx)*inv_t);
    float ei = __expf((ir-mx)*inv_t);
    float eo = __expf((og-mx)*inv_t);
    float inv_s = 1.0f/(ef+ei+eo);
    float ft = ef*inv_s, it = ei*inv_s, ot = eo*inv_s;

    f32x2 cp = *(const f32x2*)(c_prev + 2*((size_t)b*1024 + h));
    f32x2 dp = *(const f32x2*)(d_prev + 2*((size_t)b*1024 + h));

    float r0 = (1.f-ft)*cp[0], r1 = (1.f-ft)*cp[1];
    float rm2 = r0*r0 + r1*r1;
    conv_acc += rm2 + 1e-8f;
    float rmag = sqrtf(rm2 + 1e-8f);
    float cm = __expf(0.66666667f * __logf(rmag));
    float rx = r0 + 1e-10f;
    float hr = fmaxf(sqrtf(rx*rx + r1*r1), 1e-30f);
    float invhr = cm / hr;
    float comp0 = fminf(fmaxf(rx*invhr, -10.f), 10.f);
    float comp1 = fminf(fmaxf(r1*invhr, -10.f), 10.f);

    float d0 = dp[0] + 0.01f*comp0;
    float d1 = dp[1] + 0.01f*comp1;
    float dmn = sqrtf(d0*d0 + d1*d1 + 1e-8f);
    if (dmn > 20.f){ float sc = 20.f/dmn; d0*=sc; d1*=sc; }

    float gt0 = ftanh(g0), gt1 = ftanh(g1);
    float cu0 = ft*cp[0] + it*gt0;
    float cu1 = ft*cp[1] + it*gt1;
    float th = theta[h];
    float sth, cth;
    __sincosf(th, &sth, &cth);
    float c0 = cth*cu0 - sth*cu1;
    float c1 = sth*cu0 + cth*cu1;
    float cs0 = ftanh(c0), cs1 = ftanh(c1);
    float hr0 = ot*cs0, hr1 = ot*cs1;

    float hx = hr0 + 1e-10f, dx = d0 + 1e-10f;
    float hh = sqrtf(hx*hx + hr1*hr1);
    float hd = sqrtf(dx*dx + d1*d1);
    float cosd = (hx*dx + hr1*d1) / fmaxf(hh*hd, 1e-30f);
    float G = 0.5f + 0.5f*cosd;
    float h0 = G*hr0, h1 = G*hr1;
    emer_acc += h0*h0 + h1*h1 + 1e-8f;

    h0 = (h0==h0)?h0:0.f;  h1 = (h1==h1)?h1:0.f;
    c0 = (c0==c0)?c0:0.f;  c1 = (c1==c1)?c1:0.f;
    d0 = (d0==d0)?d0:0.f;  d1 = (d1==d1)?d1:0.f;

    size_t oi = 2*((size_t)b*1024 + h);
    *(f32x2*)(Hout+oi) = f32x2{h0,h1};
    *(f32x2*)(Cout+oi) = f32x2{c0,c1};
    *(f32x2*)(Dout+oi) = f32x2{d0,d1};
  }

  #pragma unroll
  for (int off=32; off; off>>=1){
    conv_acc += __shfl_down(conv_acc, off);
    emer_acc += __shfl_down(emer_acc, off);
  }
  __shared__ float sred[8];
  int wv = tid>>6, ln = tid&63;
  if (ln==0){ sred[wv]=conv_acc; sred[4+wv]=emer_acc; }
  __syncthreads();
  if (tid==0){
    float cv = sred[0]+sred[1]+sred[2]+sred[3];
    float em = sred[4]+sred[5]+sred[6]+sred[7];
    float bm = cv/(cv+em+1e-8f);
    float bt = 0.99f*bp + 0.01f*bm;
    bt = (bt==bt)?bt:0.5f;
    Bout[b] = bt;
  }
}

extern "C" void kernel_launch(void* const* d_in, const int* in_sizes, int n_in,
                              void* d_out, int out_size, void* d_ws, size_t ws_size,
                              hipStream_t stream)
{
  const float* x_t    = (const float*)d_in[0];
  const float* h_prev = (const float*)d_in[1];
  const float* c_prev = (const float*)d_in[2];
  const float* d_prev = (const float*)d_in[3];
  const float* b_prev = (const float*)d_in[4];
  const float* Wf_w   = (const float*)d_in[5];
  const float* Wf_b   = (const float*)d_in[6];
  const float* Wi_w   = (const float*)d_in[7];
  const float* Wi_b   = (const float*)d_in[8];
  const float* Wo_w   = (const float*)d_in[9];
  const float* Wo_b   = (const float*)d_in[10];
  const float* Wc_w   = (const float*)d_in[11];
  const float* Wc_b   = (const float*)d_in[12];
  const float* Wr_w   = (const float*)d_in[13];
  const float* Wr_b   = (const float*)d_in[14];
  const float* theta  = (const float*)d_in[15];

  char* W = (char*)d_ws;
  // 0: rawfio bf16 [4096][3072] (25 MB)
  u16*   rawfio = (u16*)W;
  // 50331648: Wr_hi(4M)/Wr_lo(4M)/x_lo(8M) transient; raw_g bf16 later
  u16*   Wr_hi  = (u16*)(W + 50331648);
  u16*   Wr_lo  = (u16*)(W + 50331648 + 4194304);
  u16*   x_lo   = (u16*)(W + 50331648 + 8388608);
  u16*   raw_g  = (u16*)(W + 50331648);
  // 67108864: cA bf16 [4096][5120]
  u16*   cA     = (u16*)(W + 67108864);
  // 109051904: WD3 bf16 [3072][5120] (fio), then Wc reuse
  u16*   WD     = (u16*)(W + 109051904);
  // 140509184: idx, smap; 140546048: Scmp, rawfix
  int*   idx    = (int*)(W + 140509184);
  int*   smap   = (int*)(W + 140509184 + 16388);
  float* Scmp   = (float*)(W + 140546048);
  float* rawfix = (float*)(W + 140546048 + (size_t)CAPF*2048*4);

  dim3 blk(256);

  prep0<<<15105, blk, 0, stream>>>(x_t, h_prev, cA, x_lo, Wr_w, Wr_hi, Wr_lo,
                                   b_prev, idx, smap, rawfix);
  // GEMM1 (split 3-pass) with FUSED surfaced epilogue: writes cA[:,3072:5120] + Scmp directly
  gemm128<true,false,3><<<dim3(8,32), dim3(512), 0, stream>>>(
      cA, 5120, x_lo, 1024, Wr_hi, 1024, Wr_lo,
      Wr_b, nullptr, nullptr, 0, 1024,
      d_prev, smap, Scmp, cA);
  gemm_fix_sk<<<dim3(24,8,FIX_KC), blk, 0, stream>>>(
      x_t, h_prev, Scmp, smap, Wf_w, Wi_w, Wo_w, idx, rawfix);
  cvtW3<<<15360, blk, 0, stream>>>(Wf_w, Wi_w, Wo_w, WD);
  // f/i/o merged: gemm8p NR=3 (BN=192), 256 blocks = 1/CU, bf16 output
  gemm8p<3,true,3><<<dim3(16,16), dim3(512), 0, stream>>>(
      cA, 5120, WD, 5120, Wf_b, Wi_b, Wo_b, nullptr, rawfio, 3072, 5120);
  cvt_hi<<<10240, blk, 0, stream>>>(Wc_w, WD, 2621440);
  // g: gemm2b NF=4 ring-3 (48KB LDS -> 3 blocks/CU)
  gemm2b<4,3,true,1><<<dim3(16,32), blk, 0, stream>>>(
      cA, 5120, WD, 5120, Wc_b, nullptr, nullptr, nullptr, raw_g, 2048, 5120);
  epilogue<<<4096, blk, 0, stream>>>(rawfio, raw_g, rawfix, smap, idx,
                                     Wf_b, Wi_b, Wo_b,
                                     c_prev, d_prev, b_prev, theta, (float*)d_out);
}

// Round 15
// 478.262 us; speedup vs baseline: 1.0515x; 1.0515x over previous
//
#include <hip/hip_runtime.h>
#include <math.h>

typedef unsigned short u16;
typedef unsigned int u32;
typedef u16 u16x4 __attribute__((ext_vector_type(4)));
typedef float f32x2 __attribute__((ext_vector_type(2)));
typedef float f32x4 __attribute__((ext_vector_type(4)));
typedef __bf16 bf16x8 __attribute__((ext_vector_type(8)));

#define CAPF 256

__device__ __forceinline__ u16 f2bf(float f){
  u32 u = __builtin_bit_cast(u32, f);
  u32 r = u + 0x7FFFu + ((u >> 16) & 1u);
  return (u16)(r >> 16);
}
__device__ __forceinline__ float bf2f(u16 h){
  u32 u = ((u32)h) << 16;
  return __builtin_bit_cast(float, u);
}
__device__ __forceinline__ float ftanh(float x){
  float e = __expf(2.f*x);
  return 1.f - 2.f/(e+1.f);
}

typedef __attribute__((address_space(1))) const unsigned int gas_u32;
typedef __attribute__((address_space(3))) unsigned int las_u32;
__device__ __forceinline__ void gload_lds16(const void* g, void* l){
  __builtin_amdgcn_global_load_lds((gas_u32*)g, (las_u32*)l, 16, 0, 0);
}

// ---------------- prep0: fused cvt_xh + cvt_hilo(Wr) + zero(rawfix) + flag_rows ----------------
__global__ __launch_bounds__(256) void prep0(
    const float* __restrict__ x, const float* __restrict__ h,
    u16* __restrict__ cA, u16* __restrict__ xlo,
    const float* __restrict__ Wr, u16* __restrict__ Wr_hi, u16* __restrict__ Wr_lo,
    const float* __restrict__ bp, int* __restrict__ idx, int* __restrict__ smap,
    float* __restrict__ rawfix)
{
  const int bx = blockIdx.x, tid = threadIdx.x;
  if (bx < 12288){
    int b = bx / 3, cb = bx - b*3;
    int c0 = (cb*256 + tid)*4;
    f32x4 v;
    if (c0 < 1024) v = *(const f32x4*)(x + (size_t)b*1024 + c0);
    else           v = *(const f32x4*)(h + (size_t)b*2048 + (c0-1024));
    u16x4 hi4;
    #pragma unroll
    for (int j=0;j<4;++j) hi4[j]=f2bf(v[j]);
    *(u16x4*)(cA + (size_t)b*5120 + c0) = hi4;
    if (c0 < 1024){
      u16x4 lo4;
      #pragma unroll
      for (int j=0;j<4;++j) lo4[j]=f2bf(v[j]-bf2f(hi4[j]));
      *(u16x4*)(xlo + (size_t)b*1024 + c0) = lo4;
    }
  } else if (bx < 14336){
    int i = (bx-12288)*256 + tid;
    f32x4 v = *(const f32x4*)(Wr + (size_t)i*4);
    u16x4 oh, ol;
    #pragma unroll
    for (int j=0;j<4;++j){ u16 hh=f2bf(v[j]); oh[j]=hh; ol[j]=f2bf(v[j]-bf2f(hh)); }
    *(u16x4*)(Wr_hi + (size_t)i*4) = oh;
    *(u16x4*)(Wr_lo + (size_t)i*4) = ol;
  } else if (bx < 15104){
    int i = (bx-14336)*256 + tid;
    *(f32x4*)(rawfix + (size_t)i*4) = f32x4{0.f,0.f,0.f,0.f};
  } else {
    __shared__ int cnt;
    if (tid==0) cnt=0;
    __syncthreads();
    for (int i=tid; i<4096; i+=256){
      int p = -1;
      if (bp[i] < 0.04f){
        p = atomicAdd(&cnt,1);
        if (p < CAPF) idx[1+p]=i;
      }
      smap[i] = p;
    }
    __syncthreads();
    if (tid==0) idx[0] = min(cnt, CAPF);
  }
}

// ---------------- cvtW3 / cvt_hi ----------------
__global__ __launch_bounds__(256) void cvtW3(
    const float* __restrict__ W0, const float* __restrict__ W1, const float* __restrict__ W2,
    u16* __restrict__ out)
{
  int i = blockIdx.x*256 + threadIdx.x;
  int seg = i / 1310720;
  int w = i - seg*1310720;
  const float* src = (seg==0) ? W0 : (seg==1 ? W1 : W2);
  f32x4 v = *(const f32x4*)(src + (size_t)w*4);
  u16x4 o;
  #pragma unroll
  for (int j=0;j<4;++j) o[j]=f2bf(v[j]);
  *(u16x4*)(out + (size_t)seg*5242880 + (size_t)w*4) = o;
}

__global__ __launch_bounds__(256) void cvt_hi(const float* __restrict__ in, u16* __restrict__ out, int n4){
  int i = blockIdx.x*256 + threadIdx.x;
  if (i >= n4) return;
  f32x4 v = *(const f32x4*)(in + (size_t)i*4);
  u16x4 o;
  #pragma unroll
  for (int j=0;j<4;++j) o[j]=f2bf(v[j]);
  *(u16x4*)(out + (size_t)i*4) = o;
}

// surfaced via dot-product identity. bf16 into cA[:,3072:5120]; f32 compact for flagged rows.
__global__ __launch_bounds__(256) void prep_surf(const float* __restrict__ xc, const float* __restrict__ dp,
                                                 const int* __restrict__ smap, float* __restrict__ Scmp,
                                                 u16* __restrict__ cA){
  int i = blockIdx.x*256 + threadIdx.x;
  int b = i >> 10, h = i & 1023;
  f32x2 z = *(const f32x2*)(xc + 2*(size_t)i);
  f32x2 d = *(const f32x2*)(dp + 2*(size_t)i);
  float zx = z[0] + 1e-10f, dx = d[0] + 1e-10f;
  float hz = sqrtf(zx*zx + z[1]*z[1]);
  float hd = sqrtf(dx*dx + d[1]*d[1]);
  float cosd = (zx*dx + z[1]*d[1]) / fmaxf(hz*hd, 1e-30f);
  float T = 0.5f + 0.5f*cosd;
  float dmag = sqrtf(d[0]*d[0] + d[1]*d[1] + 1e-8f);
  float dscale = sqrtf(fminf(fmaxf(dmag, 1e-6f), 20.0f));
  float s = T * dscale / (dmag + 1e-8f);
  float o0 = d[0]*s, o1 = d[1]*s;
  u32 pk = (u32)f2bf(o0) | ((u32)f2bf(o1) << 16);
  *(u32*)&cA[(size_t)b*5120 + 3072 + 2*h] = pk;
  int p = smap[b];
  if (p >= 0 && p < CAPF)
    *(f32x2*)(Scmp + ((size_t)p*1024 + h)*2) = f32x2{o0, o1};
}

// ============ gemm2b: BM=128, BN=NF*32, 256 threads (4 waves 2Mx2N), BUFS-ring half-bufs ============
#define STG2B(U, BW) do{ int uc_ = min((U), NH-1); \
    const u16* sa_ = Ah + aS + (size_t)uc_*32; \
    u16* da_ = sA + (BW)*4096 + w4*512; \
    gload_lds16(sa_, da_); \
    gload_lds16(sa_ + (size_t)64*lda, da_ + 2048); \
    const u16* sb_ = Bh + bS + (size_t)uc_*32; \
    u16* db_ = sB + (BW)*BUFB + w4*512; \
    _Pragma("unroll") for (int j_=0;j_<BNC;++j_) \
      gload_lds16(sb_ + (size_t)(j_*64)*ldb, db_ + j_*2048); \
  }while(0)

template<int NF, int BUFS, bool OUTBF, int NB>
__global__ __launch_bounds__(256) void gemm2b(
    const u16* __restrict__ Ah, int lda,
    const u16* __restrict__ Bh, int ldb,
    const float* __restrict__ bias0, const float* __restrict__ bias1, const float* __restrict__ bias2,
    float* __restrict__ Cf, u16* __restrict__ Cb, int ldc, int K)
{
  constexpr int BN   = NF*32;
  constexpr int BNC  = BN/64;
  constexpr int LPH  = 2 + BNC;
  constexpr int VN   = (BUFS-2)*LPH;
  constexpr int BUFB = BN*32;
  __shared__ u16 sA[BUFS*4096];
  __shared__ u16 sB[BUFS*BUFB];

  const int tid = threadIdx.x, lane = tid&63, w4 = tid>>6;
  const int wm = w4>>1, wn = w4&1;
  const int l16 = lane&15;

  const int gx = gridDim.x, nwg = gx*gridDim.y;
  const int lin = blockIdx.y*gx + blockIdx.x;
  const int sw = (lin&7)*(nwg>>3) + (lin>>3);
  const int m0 = (sw / gx)*128, n0 = (sw % gx)*BN;

  const int rowS = tid>>2;
  const int ksS  = (tid&3) ^ ((tid>>3)&3);
  const size_t aS = (size_t)(m0 + rowS)*lda + ksS*8;
  const size_t bS = (size_t)(n0 + rowS)*ldb + ksS*8;

  const int slot  = (lane>>4) ^ ((l16>>1)&3);
  const int abase = (wm*64 + l16)*32 + slot*8;
  const int bbase = (wn*(NF*16) + l16)*32 + slot*8;

  f32x4 acc[4][NF];
  #pragma unroll
  for (int a=0;a<4;++a)
    #pragma unroll
    for (int b=0;b<NF;++b) acc[a][b] = f32x4{0.f,0.f,0.f,0.f};

  const int NH = K>>5;

  #pragma unroll
  for (int u=0; u<BUFS-1; ++u){ STG2B(u, u); }
  asm volatile("s_waitcnt vmcnt(%0)" :: "i"(VN) : "memory");
  asm volatile("" ::: "memory");
  __builtin_amdgcn_s_barrier();

  int bufR = 0;
  for (int t=0; t<NH; ++t){
    int bufW = bufR + (BUFS-1); if (bufW >= BUFS) bufW -= BUFS;
    const u16* pa_ = sA + bufR*4096;
    const u16* pb_ = sB + bufR*BUFB;
    bf16x8 af0 = *(const bf16x8*)(pa_ + abase + 0*512);
    bf16x8 af1 = *(const bf16x8*)(pa_ + abase + 1*512);
    bf16x8 af2 = *(const bf16x8*)(pa_ + abase + 2*512);
    bf16x8 af3 = *(const bf16x8*)(pa_ + abase + 3*512);
    bf16x8 bfr[NF];
    #pragma unroll
    for (int n=0;n<NF;++n) bfr[n] = *(const bf16x8*)(pb_ + bbase + n*512);
    STG2B(t+BUFS-1, bufW);
    asm volatile("" ::: "memory");
    __builtin_amdgcn_s_barrier();
    __builtin_amdgcn_s_setprio(1);
    #pragma unroll
    for (int n=0;n<NF;++n){
      acc[0][n] = __builtin_amdgcn_mfma_f32_16x16x32_bf16(af0, bfr[n], acc[0][n],0,0,0);
      acc[1][n] = __builtin_amdgcn_mfma_f32_16x16x32_bf16(af1, bfr[n], acc[1][n],0,0,0);
      acc[2][n] = __builtin_amdgcn_mfma_f32_16x16x32_bf16(af2, bfr[n], acc[2][n],0,0,0);
      acc[3][n] = __builtin_amdgcn_mfma_f32_16x16x32_bf16(af3, bfr[n], acc[3][n],0,0,0);
    }
    __builtin_amdgcn_s_setprio(0);
    asm volatile("s_waitcnt vmcnt(%0)" :: "i"(VN) : "memory");
    asm volatile("" ::: "memory");
    __builtin_amdgcn_s_barrier();
    bufR = (bufR+1==BUFS) ? 0 : bufR+1;
  }
  asm volatile("s_waitcnt vmcnt(0)" ::: "memory");

  #pragma unroll
  for (int mf=0; mf<4; ++mf){
    int grow = m0 + wm*64 + mf*16 + (lane>>4)*4;
    #pragma unroll
    for (int n=0; n<NF; ++n){
      int gcol = n0 + wn*(NF*16) + n*16 + l16;
      float bb;
      if constexpr(NB==3) bb = (gcol<1024) ? bias0[gcol] : ((gcol<2048) ? bias1[gcol-1024] : bias2[gcol-2048]);
      else bb = bias0[gcol];
      #pragma unroll
      for (int r2=0;r2<4;++r2){
        float v = acc[mf][n][r2] + bb;
        if constexpr(OUTBF) Cb[(size_t)(grow+r2)*ldc + gcol] = f2bf(v);
        else                Cf[(size_t)(grow+r2)*ldc + gcol] = v;
      }
    }
  }
}

// ============ gemm8p: 8-phase 256-row GEMM (fio: NR=3 -> BN=192 exact-fill) ============
#define LDA8(BUF,H,MH,J) (*(const bf16x8*)(sAc + ((BUF)*2+(H))*16384 + abase + (MH)*4096 + (J)*1024))
#define LDB8(BUF,H,N)    (*(const bf16x8*)(sBc + ((BUF)*2+(H))*16384 + bbase + (N)*1024))
#define STG_A8(BUF,H,TT) { const u16* s_ = Ah + aS + (size_t)(TT)*64 + (H)*32; \
    gload_lds16(s_, dA + ((BUF)*2+(H))*8192); \
    gload_lds16(s_ + aS2, dA + ((BUF)*2+(H))*8192 + 4096); }
#define STG_B8(BUF,H,TT) { const u16* s_ = Bh + bS + (size_t)(TT)*64 + (H)*32; \
    gload_lds16(s_, dB + ((BUF)*2+(H))*8192); \
    gload_lds16(s_ + bS2, dB + ((BUF)*2+(H))*8192 + 4096); }
#define PH8(BUF,H,MH,RB,STG,DOW) do{ \
    bf16x8 af0 = LDA8(BUF,H,MH,0), af1 = LDA8(BUF,H,MH,1), af2 = LDA8(BUF,H,MH,2), af3 = LDA8(BUF,H,MH,3); \
    if (RB){ _Pragma("unroll") for(int n_=0;n_<NR;++n_) bfr[n_] = LDB8(BUF,H,n_); } \
    STG; \
    asm volatile("" ::: "memory"); \
    __builtin_amdgcn_s_barrier(); \
    __builtin_amdgcn_s_setprio(1); \
    _Pragma("unroll") for(int n_=0;n_<NR;++n_){ \
      acc[(MH)*4+0][n_] = __builtin_amdgcn_mfma_f32_16x16x32_bf16(af0, bfr[n_], acc[(MH)*4+0][n_],0,0,0); \
      acc[(MH)*4+1][n_] = __builtin_amdgcn_mfma_f32_16x16x32_bf16(af1, bfr[n_], acc[(MH)*4+1][n_],0,0,0); \
      acc[(MH)*4+2][n_] = __builtin_amdgcn_mfma_f32_16x16x32_bf16(af2, bfr[n_], acc[(MH)*4+2][n_],0,0,0); \
      acc[(MH)*4+3][n_] = __builtin_amdgcn_mfma_f32_16x16x32_bf16(af3, bfr[n_], acc[(MH)*4+3][n_],0,0,0); } \
    __builtin_amdgcn_s_setprio(0); \
    if (DOW) { asm volatile("s_waitcnt vmcnt(%0)" :: "i"(VN) : "memory"); } \
    asm volatile("" ::: "memory"); \
    __builtin_amdgcn_s_barrier(); \
  }while(0)

template<int NR, bool OUTBF, int NB>
__global__ __launch_bounds__(512) void gemm8p(
    const u16* __restrict__ Ah, int lda,
    const u16* __restrict__ Bh, int ldb,
    const float* __restrict__ bias0, const float* __restrict__ bias1, const float* __restrict__ bias2,
    float* __restrict__ Cf, u16* __restrict__ Cb, int ldc, int K)
{
  constexpr int VN   = 8;
  __shared__ u16 sA[4*8192];
  __shared__ u16 sB[4*8192];
  const char* sAc = (const char*)sA;
  const char* sBc = (const char*)sB;

  const int tid = threadIdx.x, lane = tid&63, w8 = tid>>6;
  const int wr = w8>>2, wc = w8&3;
  const int l16 = lane&15;

  const int gx = gridDim.x, nwg = gx*gridDim.y;
  const int lin = blockIdx.y*gx + blockIdx.x;
  const int sw = (lin&7)*(nwg>>3) + (lin>>3);
  const int m0 = (sw / gx)*256, n0 = (sw % gx)*(NR*64);

  const int rowS  = tid>>2;
  const int ksS   = (tid&3) ^ ((tid>>3)&3);
  const size_t aS = (size_t)(m0 + rowS)*lda + ksS*8;
  const size_t aS2= (size_t)128*lda;
  const size_t bS = (size_t)(n0 + rowS)*ldb + ksS*8;
  const size_t bS2= (size_t)128*ldb;
  u16* dA = sA + w8*512;
  u16* dB = sB + w8*512;

  const int aslot = (lane>>4) ^ ((l16>>1)&3);
  const int abase = (wr*128 + l16)*64 + aslot*16;
  const int bbase = (wc*(NR*16) + l16)*64 + aslot*16;

  f32x4 acc[8][NR];
  #pragma unroll
  for (int a=0;a<8;++a)
    #pragma unroll
    for (int b=0;b<NR;++b) acc[a][b] = f32x4{0.f,0.f,0.f,0.f};
  bf16x8 bfr[NR];

  const int NT = K>>6, NITER = K>>7;

  STG_A8(0,0,0) STG_B8(0,0,0) STG_A8(0,1,0) STG_B8(0,1,0) STG_A8(1,0,1) STG_B8(1,0,1)
  asm volatile("s_waitcnt vmcnt(%0)" :: "i"(VN) : "memory");
  asm volatile("" ::: "memory");
  __builtin_amdgcn_s_barrier();

  for (int i=0; i<NITER; ++i){
    const int t1 = 2*i+1;
    const int ta = min(2*i+2, NT-1);
    const int tb = min(2*i+3, NT-1);
    PH8(0,0,0,true,  STG_A8(1,1,t1), false);
    PH8(0,0,1,false, STG_B8(1,1,t1), true);
    PH8(0,1,0,true,  STG_A8(0,0,ta), false);
    PH8(0,1,1,false, STG_B8(0,0,ta), true);
    PH8(1,0,0,true,  STG_A8(0,1,ta), false);
    PH8(1,0,1,false, STG_B8(0,1,ta), true);
    PH8(1,1,0,true,  STG_A8(1,0,tb), false);
    PH8(1,1,1,false, STG_B8(1,0,tb), true);
  }
  asm volatile("s_waitcnt vmcnt(0)" ::: "memory");

  #pragma unroll
  for (int mf=0; mf<8; ++mf){
    int grow = m0 + wr*128 + mf*16 + (lane>>4)*4;
    #pragma unroll
    for (int n=0; n<NR; ++n){
      int gcol = n0 + wc*(NR*16) + n*16 + l16;
      float bb;
      if constexpr(NB==3) bb = (gcol<1024) ? bias0[gcol] : ((gcol<2048) ? bias1[gcol-1024] : bias2[gcol-2048]);
      else bb = bias0[gcol];
      #pragma unroll
      for (int r2=0;r2<4;++r2){
        float v = acc[mf][n][r2] + bb;
        if constexpr(OUTBF) Cb[(size_t)(grow+r2)*ldc + gcol] = f2bf(v);
        else                Cf[(size_t)(grow+r2)*ldc + gcol] = v;
      }
    }
  }
}

// ============ gemm128: BM=128 BN=256 BK=32, BUFS-ring (GEMM1 split path, plain epilogue) ============
#define STG128(USRC, BW) do{ int u_=(USRC)<NT?(USRC):NT-1; \
    { const u16* s_=Ah+aS+(size_t)u_*32; gload_lds16(s_, sA+(BW)*4096+ldsb); } \
    { const u16* s_=Bh+bS+(size_t)u_*32; gload_lds16(s_, sB+(BW)*8192+ldsb); \
      gload_lds16(s_+bS2, sB+(BW)*8192+4096+ldsb); } \
    if constexpr(SPLIT){ \
      const u16* s2_=Al+aSl+(size_t)u_*32; gload_lds16(s2_, sAl+(BW)*4096+ldsb); \
      const u16* s3_=Bl+bS+(size_t)u_*32;  gload_lds16(s3_, sBl+(BW)*8192+ldsb); \
      gload_lds16(s3_+bS2, sBl+(BW)*8192+4096+ldsb); } \
  }while(0)

template<bool SPLIT, bool OUTBF, int BUFS>
__global__ __launch_bounds__(512) void gemm128(
    const u16* __restrict__ Ah, int lda,
    const u16* __restrict__ Al, int ldal,
    const u16* __restrict__ Bh, int ldb,
    const u16* __restrict__ Bl,
    const float* __restrict__ bias0,
    float* __restrict__ Cf, u16* __restrict__ Cb, int ldc, int K)
{
  constexpr int LPS = SPLIT ? 6 : 3;
  constexpr int VN  = (BUFS-2)*LPS;
  constexpr int PRE = BUFS-1;
  __shared__ u16 sA [BUFS*4096];
  __shared__ u16 sB [BUFS*8192];
  __shared__ u16 sAl[SPLIT?BUFS*4096:8];
  __shared__ u16 sBl[SPLIT?BUFS*8192:8];

  const int tid=threadIdx.x, lane=tid&63, w8=tid>>6;
  const int wr=w8>>2, wc=w8&3, l16=lane&15;

  const int gx=gridDim.x, nwg=gx*gridDim.y;
  const int lin=blockIdx.y*gx+blockIdx.x;
  const int sw=(lin&7)*(nwg>>3)+(lin>>3);
  const int m0=(sw/gx)*128, n0=(sw%gx)*256;

  const int rowS=tid>>2;
  const int ksS=(tid&3)^((tid>>3)&3);
  const size_t aS =(size_t)(m0+rowS)*lda  + ksS*8;
  const size_t aSl=(size_t)(m0+rowS)*(size_t)ldal + ksS*8;
  const size_t bS =(size_t)(n0+rowS)*ldb  + ksS*8;
  const size_t bS2=(size_t)128*ldb;
  const int ldsb = w8*512;

  const int aslot=(lane>>4)^((l16>>1)&3);
  const int abase=(wr*64+l16)*64 + aslot*16;
  const int bbase=(wc*64+l16)*64 + aslot*16;

  f32x4 acc[4][4];
  #pragma unroll
  for (int a=0;a<4;++a)
    #pragma unroll
    for (int b=0;b<4;++b) acc[a][b] = f32x4{0.f,0.f,0.f,0.f};

  const int NT = K>>5;

  #pragma unroll
  for (int u=0; u<PRE; ++u){ STG128(u,u); }
  asm volatile("s_waitcnt vmcnt(%0)" :: "i"(VN) : "memory");
  asm volatile("" ::: "memory");
  __builtin_amdgcn_s_barrier();

  int bufR = 0;
  for (int t=0; t<NT; ++t){
    int bufW = (bufR==0) ? BUFS-1 : bufR-1;
    const char* sAc=(const char*)sA  + bufR*8192;
    const char* sBc=(const char*)sB  + bufR*16384;
    const char* sAlc=(const char*)sAl + bufR*8192;
    const char* sBlc=(const char*)sBl + bufR*16384;
    bf16x8 af[4], bf[4], afl[4], bfl[4];
    #pragma unroll
    for (int f=0; f<4; ++f){
      af[f] = *(const bf16x8*)(sAc + abase + f*1024);
      bf[f] = *(const bf16x8*)(sBc + bbase + f*1024);
      if constexpr(SPLIT){
        afl[f] = *(const bf16x8*)(sAlc + abase + f*1024);
        bfl[f] = *(const bf16x8*)(sBlc + bbase + f*1024);
      }
    }
    STG128(t+PRE, bufW);
    asm volatile("" ::: "memory");
    __builtin_amdgcn_s_barrier();
    __builtin_amdgcn_s_setprio(1);
    #pragma unroll
    for (int mf=0; mf<4; ++mf){
      #pragma unroll
      for (int nf=0; nf<4; ++nf){
        acc[mf][nf] = __builtin_amdgcn_mfma_f32_16x16x32_bf16(af[mf], bf[nf], acc[mf][nf],0,0,0);
        if constexpr(SPLIT){
          acc[mf][nf] = __builtin_amdgcn_mfma_f32_16x16x32_bf16(afl[mf], bf[nf],  acc[mf][nf],0,0,0);
          acc[mf][nf] = __builtin_amdgcn_mfma_f32_16x16x32_bf16(af[mf],  bfl[nf], acc[mf][nf],0,0,0);
        }
      }
    }
    __builtin_amdgcn_s_setprio(0);
    asm volatile("s_waitcnt vmcnt(%0)" :: "i"(VN) : "memory");
    asm volatile("" ::: "memory");
    __builtin_amdgcn_s_barrier();
    bufR = (bufR+1==BUFS) ? 0 : bufR+1;
  }
  asm volatile("s_waitcnt vmcnt(0)" ::: "memory");

  #pragma unroll
  for (int mf=0; mf<4; ++mf){
    int grow = m0 + wr*64 + mf*16 + (lane>>4)*4;
    #pragma unroll
    for (int nf=0; nf<4; ++nf){
      int gcol = n0 + wc*64 + nf*16 + l16;
      float bb = bias0[gcol];
      #pragma unroll
      for (int r2=0;r2<4;++r2){
        float v = acc[mf][nf][r2] + bb;
        if constexpr(OUTBF) Cb[(size_t)(grow+r2)*ldc + gcol] = f2bf(v);
        else                Cf[(size_t)(grow+r2)*ldc + gcol] = v;
      }
    }
  }
}

// ---------------- fixup: precise 3-pass for flagged rows, SPLIT-K, compact output ----------------
#define LSTR 40
#define FIX_KC 16
#define FIX_KLEN 320
__global__ __launch_bounds__(256) void gemm_fix_sk(
    const float* __restrict__ Xs, const float* __restrict__ Hs,
    const float* __restrict__ Scmp, const int* __restrict__ smap,
    const float* __restrict__ W0, const float* __restrict__ W1, const float* __restrict__ W2,
    const int* __restrict__ cr, float* __restrict__ Cfix)
{
  const int count = cr[0];
  const int m0 = blockIdx.y * 128;
  if (m0 >= count) return;
  const int* rows = cr + 1;
  const int kbeg = blockIdx.z * FIX_KLEN;
  const int kend = kbeg + FIX_KLEN;

  __shared__ u16 sAh[128*LSTR];
  __shared__ u16 sAl[128*LSTR];
  __shared__ u16 sBh[128*LSTR];
  __shared__ u16 sBl[128*LSTR];

  const int tid = threadIdx.x;
  const int n0 = blockIdx.x * 128;
  int seg = n0 >> 10;
  const float* W = (seg==0) ? W0 : (seg==1 ? W1 : W2);
  int nw = n0 & 1023;

  const int wave = tid >> 6, lane = tid & 63;
  const int wm = wave >> 1, wn = wave & 1;
  const int l16 = lane & 15, lk8 = (lane >> 4) * 8;

  f32x4 acc[4][4];
  #pragma unroll
  for (int a=0;a<4;++a)
    #pragma unroll
    for (int b=0;b<4;++b) acc[a][b] = f32x4{0.f,0.f,0.f,0.f};

  for (int k0 = kbeg; k0 < kend; k0 += 32){
    #pragma unroll
    for (int i=0;i<4;++i){
      int flat = tid + i*256;
      int r  = flat >> 3;
      int c4 = flat & 7;
      int kk = k0 + c4*4;
      int mi = min(m0 + r, count-1);
      int mrow = rows[mi];
      const float* srcA;
      if (kk < 1024)      srcA = Xs + (size_t)mrow*1024 + kk;
      else if (kk < 3072) srcA = Hs + (size_t)mrow*2048 + (kk - 1024);
      else                srcA = Scmp + (size_t)smap[mrow]*2048 + (kk - 3072);
      f32x4 va = *(const f32x4*)srcA;
      f32x4 vb = *(const f32x4*)(W + (size_t)(nw + r)*5120 + kk);
      u16x4 ah, bh, al, bl;
      #pragma unroll
      for (int j=0;j<4;++j){
        u16 hA = f2bf(va[j]); ah[j] = hA; al[j] = f2bf(va[j] - bf2f(hA));
        u16 hB = f2bf(vb[j]); bh[j] = hB; bl[j] = f2bf(vb[j] - bf2f(hB));
      }
      int o = r*LSTR + c4*4;
      *(u16x4*)&sAh[o] = ah;
      *(u16x4*)&sBh[o] = bh;
      *(u16x4*)&sAl[o] = al;
      *(u16x4*)&sBl[o] = bl;
    }
    __syncthreads();
    bf16x8 fah[4], fbh[4], fal[4], fbl[4];
    #pragma unroll
    for (int f=0; f<4; ++f){
      int ra  = (wm*64 + f*16 + l16)*LSTR + lk8;
      int rb2 = (wn*64 + f*16 + l16)*LSTR + lk8;
      fah[f] = *(const bf16x8*)&sAh[ra];
      fbh[f] = *(const bf16x8*)&sBh[rb2];
      fal[f] = *(const bf16x8*)&sAl[ra];
      fbl[f] = *(const bf16x8*)&sBl[rb2];
    }
    #pragma unroll
    for (int fm=0; fm<4; ++fm){
      #pragma unroll
      for (int fn=0; fn<4; ++fn){
        acc[fm][fn] = __builtin_amdgcn_mfma_f32_16x16x32_bf16(fah[fm], fbh[fn], acc[fm][fn], 0,0,0);
        acc[fm][fn] = __builtin_amdgcn_mfma_f32_16x16x32_bf16(fal[fm], fbh[fn], acc[fm][fn], 0,0,0);
        acc[fm][fn] = __builtin_amdgcn_mfma_f32_16x16x32_bf16(fah[fm], fbl[fn], acc[fm][fn], 0,0,0);
      }
    }
    __syncthreads();
  }

  #pragma unroll
  for (int fm=0; fm<4; ++fm){
    int trow = wm*64 + fm*16 + (lane>>4)*4;
    #pragma unroll
    for (int fn=0; fn<4; ++fn){
      int lcol = wn*64 + fn*16 + l16;
      #pragma unroll
      for (int r2=0;r2<4;++r2){
        int mi = m0 + trow + r2;
        if (mi < count){
          atomicAdd(&Cfix[(size_t)mi*3072 + (n0 + lcol)], acc[fm][fn][r2]);
        }
      }
    }
  }
}

// ---------------- epilogue (rawfio bf16; flagged rows read compact rawfix + bias) ----------------
__global__ __launch_bounds__(256) void epilogue(
    const u16* __restrict__ rawfio, const u16* __restrict__ rawg,
    const float* __restrict__ rawfix, const int* __restrict__ smap, const int* __restrict__ cr,
    const float* __restrict__ bf0, const float* __restrict__ bf1, const float* __restrict__ bf2,
    const float* __restrict__ c_prev, const float* __restrict__ d_prev,
    const float* __restrict__ b_prev, const float* __restrict__ theta,
    float* __restrict__ out)
{
  const int b = blockIdx.x;
  const int tid = threadIdx.x;
  float* Hout = out;
  float* Cout = out + (size_t)8388608;
  float* Dout = out + (size_t)16777216;
  float* Bout = out + (size_t)25165824;
  const float bp = b_prev[b];
  const float inv_t = 1.0f / (2.0f*bp + 1e-4f);
  float conv_acc = 0.f, emer_acc = 0.f;
  const size_t rb3 = (size_t)b*3072;
  const size_t rg = (size_t)b*2048;
  const int p = smap[b];
  const bool fx = (p >= 0 && p < cr[0]);
  const size_t rfx = (size_t)p*3072;

  #pragma unroll
  for (int j=0;j<4;++j){
    int h = tid + j*256;
    float fr, ir, og;
    if (fx){
      fr = rawfix[rfx + h]        + bf0[h];
      ir = rawfix[rfx + 1024 + h] + bf1[h];
      og = rawfix[rfx + 2048 + h] + bf2[h];
    } else {
      fr = bf2f(rawfio[rb3 + h]);
      ir = bf2f(rawfio[rb3 + 1024 + h]);
      og = bf2f(rawfio[rb3 + 2048 + h]);
    }
    float g0 = bf2f(rawg[rg + h]);
    float g1 = bf2f(rawg[rg + 1024 + h]);

    float mx = fmaxf(fr, fmaxf(ir, og));
    float ef = __expf((fr-mx)*inv_t);
    float ei = __expf((ir-mx)*inv_t);
    float eo = __expf((og-mx)*inv_t);
    float inv_s = 1.0f/(ef+ei+eo);
    float ft = ef*inv_s, it = ei*inv_s, ot = eo*inv_s;

    f32x2 cp = *(const f32x2*)(c_prev + 2*((size_t)b*1024 + h));
    f32x2 dp = *(const f32x2*)(d_prev + 2*((size_t)b*1024 + h));

    float r0 = (1.f-ft)*cp[0], r1 = (1.f-ft)*cp[1];
    float rm2 = r0*r0 + r1*r1;
    conv_acc += rm2 + 1e-8f;
    float rmag = sqrtf(rm2 + 1e-8f);
    float cm = __expf(0.66666667f * __logf(rmag));
    float rx = r0 + 1e-10f;
    float hr = fmaxf(sqrtf(rx*rx + r1*r1), 1e-30f);
    float invhr = cm / hr;
    float comp0 = fminf(fmaxf(rx*invhr, -10.f), 10.f);
    float comp1 = fminf(fmaxf(r1*invhr, -10.f), 10.f);

    float d0 = dp[0] + 0.01f*comp0;
    float d1 = dp[1] + 0.01f*comp1;
    float dmn = sqrtf(d0*d0 + d1*d1 + 1e-8f);
    if (dmn > 20.f){ float sc = 20.f/dmn; d0*=sc; d1*=sc; }

    float gt0 = ftanh(g0), gt1 = ftanh(g1);
    float cu0 = ft*cp[0] + it*gt0;
    float cu1 = ft*cp[1] + it*gt1;
    float th = theta[h];
    float sth, cth;
    __sincosf(th, &sth, &cth);
    float c0 = cth*cu0 - sth*cu1;
    float c1 = sth*cu0 + cth*cu1;
    float cs0 = ftanh(c0), cs1 = ftanh(c1);
    float hr0 = ot*cs0, hr1 = ot*cs1;

    float hx = hr0 + 1e-10f, dx = d0 + 1e-10f;
    float hh = sqrtf(hx*hx + hr1*hr1);
    float hd = sqrtf(dx*dx + d1*d1);
    float cosd = (hx*dx + hr1*d1) / fmaxf(hh*hd, 1e-30f);
    float G = 0.5f + 0.5f*cosd;
    float h0 = G*hr0, h1 = G*hr1;
    emer_acc += h0*h0 + h1*h1 + 1e-8f;

    h0 = (h0==h0)?h0:0.f;  h1 = (h1==h1)?h1:0.f;
    c0 = (c0==c0)?c0:0.f;  c1 = (c1==c1)?c1:0.f;
    d0 = (d0==d0)?d0:0.f;  d1 = (d1==d1)?d1:0.f;

    size_t oi = 2*((size_t)b*1024 + h);
    *(f32x2*)(Hout+oi) = f32x2{h0,h1};
    *(f32x2*)(Cout+oi) = f32x2{c0,c1};
    *(f32x2*)(Dout+oi) = f32x2{d0,d1};
  }

  #pragma unroll
  for (int off=32; off; off>>=1){
    conv_acc += __shfl_down(conv_acc, off);
    emer_acc += __shfl_down(emer_acc, off);
  }
  __shared__ float sred[8];
  int wv = tid>>6, ln = tid&63;
  if (ln==0){ sred[wv]=conv_acc; sred[4+wv]=emer_acc; }
  __syncthreads();
  if (tid==0){
    float cv = sred[0]+sred[1]+sred[2]+sred[3];
    float em = sred[4]+sred[5]+sred[6]+sred[7];
    float bm = cv/(cv+em+1e-8f);
    float bt = 0.99f*bp + 0.01f*bm;
    bt = (bt==bt)?bt:0.5f;
    Bout[b] = bt;
  }
}

extern "C" void kernel_launch(void* const* d_in, const int* in_sizes, int n_in,
                              void* d_out, int out_size, void* d_ws, size_t ws_size,
                              hipStream_t stream)
{
  const float* x_t    = (const float*)d_in[0];
  const float* h_prev = (const float*)d_in[1];
  const float* c_prev = (const float*)d_in[2];
  const float* d_prev = (const float*)d_in[3];
  const float* b_prev = (const float*)d_in[4];
  const float* Wf_w   = (const float*)d_in[5];
  const float* Wf_b   = (const float*)d_in[6];
  const float* Wi_w   = (const float*)d_in[7];
  const float* Wi_b   = (const float*)d_in[8];
  const float* Wo_w   = (const float*)d_in[9];
  const float* Wo_b   = (const float*)d_in[10];
  const float* Wc_w   = (const float*)d_in[11];
  const float* Wc_b   = (const float*)d_in[12];
  const float* Wr_w   = (const float*)d_in[13];
  const float* Wr_b   = (const float*)d_in[14];
  const float* theta  = (const float*)d_in[15];

  char* W = (char*)d_ws;
  // 0: xc f32 [4096][2048] (33.5MB) transient; later rawfio bf16 [4096][3072] (25MB) overwrites
  float* xc     = (float*)W;
  u16*   rawfio = (u16*)W;
  // 50331648: Wr_hi(4M)/Wr_lo(4M)/x_lo(8M) transient; raw_g bf16 later
  u16*   Wr_hi  = (u16*)(W + 50331648);
  u16*   Wr_lo  = (u16*)(W + 50331648 + 4194304);
  u16*   x_lo   = (u16*)(W + 50331648 + 8388608);
  u16*   raw_g  = (u16*)(W + 50331648);
  // 67108864: cA bf16 [4096][5120]
  u16*   cA     = (u16*)(W + 67108864);
  // 109051904: WD3 bf16 [3072][5120] (fio), then Wc reuse
  u16*   WD     = (u16*)(W + 109051904);
  // 140509184: idx, smap; 140546048: Scmp, rawfix
  int*   idx    = (int*)(W + 140509184);
  int*   smap   = (int*)(W + 140509184 + 16388);
  float* Scmp   = (float*)(W + 140546048);
  float* rawfix = (float*)(W + 140546048 + (size_t)CAPF*2048*4);

  dim3 blk(256);

  prep0<<<15105, blk, 0, stream>>>(x_t, h_prev, cA, x_lo, Wr_w, Wr_hi, Wr_lo,
                                   b_prev, idx, smap, rawfix);
  // GEMM1 (split 3-pass, plain epilogue): xc = x @ Wr^T + b
  gemm128<true,false,3><<<dim3(8,32), dim3(512), 0, stream>>>(
      cA, 5120, x_lo, 1024, Wr_hi, 1024, Wr_lo,
      Wr_b, xc, nullptr, 2048, 1024);
  // surfaced -> cA[:,3072:5120] + compact Scmp
  prep_surf<<<16384, blk, 0, stream>>>(xc, d_prev, smap, Scmp, cA);
  gemm_fix_sk<<<dim3(24,8,FIX_KC), blk, 0, stream>>>(
      x_t, h_prev, Scmp, smap, Wf_w, Wi_w, Wo_w, idx, rawfix);
  cvtW3<<<15360, blk, 0, stream>>>(Wf_w, Wi_w, Wo_w, WD);
  // f/i/o merged: gemm8p NR=3 (BN=192), 256 blocks = 1/CU, bf16 output (xc now dead)
  gemm8p<3,true,3><<<dim3(16,16), dim3(512), 0, stream>>>(
      cA, 5120, WD, 5120, Wf_b, Wi_b, Wo_b, nullptr, rawfio, 3072, 5120);
  cvt_hi<<<10240, blk, 0, stream>>>(Wc_w, WD, 2621440);
  // g: gemm2b NF=4 ring-3 (48KB LDS)
  gemm2b<4,3,true,1><<<dim3(16,32), blk, 0, stream>>>(
      cA, 5120, WD, 5120, Wc_b, nullptr, nullptr, nullptr, raw_g, 2048, 5120);
  epilogue<<<4096, blk, 0, stream>>>(rawfio, raw_g, rawfix, smap, idx,
                                     Wf_b, Wi_b, Wo_b,
                                     c_prev, d_prev, b_prev, theta, (float*)d_out);
}